// Round 9
// baseline (251.034 us; speedup 1.0000x reference)
//
#include <hip/hip_runtime.h>

// FiLM block, MI355X. I/O fp32; compute bf16 MFMA (A=weights, B=tokens,
// C col=token), fp32 accum. R9: occupancy attack.
// R7/R8 falsified "DS-bound": cutting DS ops didn't help. film is
// dependency-chain bound at 2 waves/SIMD. Fix: LDS 74->52 KB (W1' only +
// 64-row h; W0/W2 frags in registers) -> 3 blocks/CU, 3 waves/SIMD; bias
// init loads in-loop (frees 64 VGPR); launch_bounds(256,3).
#define NTOK  32768
#define CIN   64
#define HDIM  128
#define O_CH  16
#define F2    16
#define SLOPE 0.01f
#define EPS   1e-5f

// LDS (shorts): W1' padded image + 64-row h-buffer.
// stride 136: 16B-aligned rows, lo16*68 mod 32 -> max 2-way conflict (free).
#define SW1_STRIDE 136
#define SH_STRIDE  136
#define SW1_SHORTS (128 * SW1_STRIDE)    // 17408
#define SH_OFF     SW1_SHORTS
#define SMEM_TOT   (SW1_SHORTS + 64 * SH_STRIDE)  // 26112 sh = 52224 B -> 3 blk/CU

// d_ws layout (bytes); ~5.1 MB total.
#define W0G_OFF    0
#define W0G_BYTES  ((size_t)O_CH * HDIM * CIN * 2)           // 262144
#define W2G_OFF    (W0G_OFF + W0G_BYTES)
#define W2G_BYTES  ((size_t)O_CH * F2 * HDIM * 2)            // 65536
#define W1I_OFF    (W2G_OFF + W2G_BYTES)
#define W1I_BYTES  ((size_t)O_CH * SW1_SHORTS * 2)           // 557056
#define XBF_OFF    (W1I_OFF + W1I_BYTES)
#define XBF_BYTES  ((size_t)NTOK * CIN * 2)                  // 4194304
#define B0F_OFF    (XBF_OFF + XBF_BYTES)
#define B0F_BYTES  ((size_t)O_CH * HDIM * 4)
#define B1F_OFF    (B0F_OFF + B0F_BYTES)
#define B1F_BYTES  ((size_t)O_CH * HDIM * 4)
#define B2F_OFF    (B1F_OFF + B1F_BYTES)
#define B2F_BYTES  ((size_t)O_CH * F2 * 4)

typedef __attribute__((ext_vector_type(8))) short bf16x8;
typedef __attribute__((ext_vector_type(4))) short bf16x4;
typedef __attribute__((ext_vector_type(4))) float f32x4;

__device__ __forceinline__ unsigned short f2b(float f) {
  union { float f; unsigned int i; } v;
  v.f = f;
  unsigned int i = v.i;
  unsigned int r = (i + 0x7fffu + ((i >> 16) & 1u)) >> 16;  // RNE
  return (unsigned short)r;
}
__device__ __forceinline__ float leaky(float t) {
  return fmaxf(t, SLOPE * t);   // identical to t>=0?t:0.01t (0.01t>t for t<0)
}
__device__ __forceinline__ bf16x8 cvt8(const float* p) {
  float4 a = *(const float4*)p;
  float4 b = *(const float4*)(p + 4);
  bf16x8 r;
  r[0] = (short)f2b(a.x); r[1] = (short)f2b(a.y);
  r[2] = (short)f2b(a.z); r[3] = (short)f2b(a.w);
  r[4] = (short)f2b(b.x); r[5] = (short)f2b(b.y);
  r[6] = (short)f2b(b.z); r[7] = (short)f2b(b.w);
  return r;
}
__device__ __forceinline__ bf16x8 cvt8s(const float* p, const float* s) {
  bf16x8 r;
#pragma unroll
  for (int i = 0; i < 8; ++i) r[i] = (short)f2b(p[i] * s[i]);
  return r;
}

// leaky + LayerNorm on C-layout (col=token=lane&15, row=h). Lane holds 32 h
// of one token; butterfly xor 16,32 finishes the 128-sum. bf16 ds_write_b64.
// sh NOT restrict (layer-1/2 read these rows via smem; R5 post-mortem).
__device__ __forceinline__ void leaky_ln_store(
    const f32x4* acc, unsigned short* sh, int shrow, int quad) {
  float v[8][4];
  float s1 = 0.f, s2 = 0.f;
#pragma unroll
  for (int nt = 0; nt < 8; ++nt) {
#pragma unroll
    for (int r = 0; r < 4; ++r) {
      float t = leaky(acc[nt][r]);        // bias folded into C-init
      v[nt][r] = t;
      s1 += t;
      s2 += t * t;
    }
  }
  s1 += __shfl_xor(s1, 16); s2 += __shfl_xor(s2, 16);
  s1 += __shfl_xor(s1, 32); s2 += __shfl_xor(s2, 32);
  float mu = s1 * (1.0f / 128.0f);
  float var = s2 * (1.0f / 128.0f) - mu * mu;
  float rs = rsqrtf(var + EPS);
#pragma unroll
  for (int nt = 0; nt < 8; ++nt) {
    bf16x4 p;
#pragma unroll
    for (int r = 0; r < 4; ++r)
      p[r] = (short)f2b((v[nt][r] - mu) * rs);
    *(bf16x4*)&sh[shrow * SH_STRIDE + nt * 16 + quad * 4] = p;
  }
}

// prep: blocks 0..15 -> per-o images (W0 bf16 flat; W2' gamma-folded flat;
// W1' gamma-folded padded image; folded biases). blocks 16+ -> x bf16.
__global__ __launch_bounds__(256) void prep(
    const float* __restrict__ x,
    const float* __restrict__ W0, const float* __restrict__ b0,
    const float* __restrict__ g0, const float* __restrict__ be0,
    const float* __restrict__ W1, const float* __restrict__ b1,
    const float* __restrict__ g1, const float* __restrict__ be1,
    const float* __restrict__ W2, const float* __restrict__ b2,
    unsigned short* __restrict__ w0g, unsigned short* __restrict__ w2g,
    unsigned short* __restrict__ w1i, unsigned short* __restrict__ xbf,
    float* __restrict__ b0f, float* __restrict__ b1f,
    float* __restrict__ b2f) {
  const int bid = blockIdx.x, tid = threadIdx.x;
  if (bid < 16) {
    const int o = bid;
    __shared__ float sg0[HDIM], sbe0[HDIM], sg1[HDIM], sbe1[HDIM];
    if (tid < 128) {
      sg0[tid]  = g0 [o * HDIM + tid];
      sbe0[tid] = be0[o * HDIM + tid];
      sg1[tid]  = g1 [o * HDIM + tid];
      sbe1[tid] = be1[o * HDIM + tid];
    }
    __syncthreads();
    const float* w0 = W0 + (size_t)o * HDIM * CIN;
    for (int c = tid; c < (HDIM * CIN) / 8; c += 256)          // 1024
      *(bf16x8*)&w0g[(size_t)o * HDIM * CIN + c * 8] = cvt8(w0 + c * 8);
    const float* w1 = W1 + (size_t)o * HDIM * HDIM;
    unsigned short* img = w1i + (size_t)o * SW1_SHORTS;
    for (int c = tid; c < (HDIM * HDIM) / 8; c += 256) {       // 2048
      int n = c >> 4, k8 = c & 15;
      *(bf16x8*)&img[n * SW1_STRIDE + k8 * 8] =
          cvt8s(w1 + c * 8, sg0 + k8 * 8);           // W1' = W1 * g0[k]
    }
    const float* w2 = W2 + (size_t)o * F2 * HDIM;
    for (int c = tid; c < (F2 * HDIM) / 8; c += 256)           // 256
      *(bf16x8*)&w2g[(size_t)o * F2 * HDIM + c * 8] =
          cvt8s(w2 + c * 8, sg1 + (c & 15) * 8);     // W2' = W2 * g1[k], flat
    if (tid < 128) {
      b0f[o * HDIM + tid] = b0[o * HDIM + tid];
      float d = 0.f;
      const float* w1r = w1 + (size_t)tid * HDIM;
      for (int k = 0; k < HDIM; ++k) d += w1r[k] * sbe0[k];
      b1f[o * HDIM + tid] = b1[o * HDIM + tid] + d;  // b1' = b1 + W1*be0
    } else if (tid < 144) {
      int f = tid - 128;
      float d = 0.f;
      const float* w2r = w2 + (size_t)f * HDIM;
      for (int k = 0; k < HDIM; ++k) d += w2r[k] * sbe1[k];
      b2f[o * F2 + f] = b2[o * F2 + f] + d;          // b2' = b2 + W2*be1
    }
  } else {
    int idx = (bid - 16) * 256 + tid;
    *(bf16x8*)&xbf[(size_t)idx * 8] = cvt8(x + (size_t)idx * 8);
  }
}

// film_main: block = one o x 256 tokens (4 waves x 4 m-tiles of 16 tokens).
// W0/W2 frags in registers; W1' in LDS; h 64 rows. 52.2 KB LDS -> 3 blk/CU.
// bid = q*128 + o*8 + c (XCD output write-combine, R6-validated).
__global__ __launch_bounds__(256, 3) void film_main(
    const unsigned short* __restrict__ xbf,
    const unsigned short* __restrict__ w0g,
    const unsigned short* __restrict__ w2g,
    const unsigned short* __restrict__ w1i,
    const float* __restrict__ b0f, const float* __restrict__ b1f,
    const float* __restrict__ b2f,
    float* __restrict__ out) {
  __shared__ unsigned short smem[SMEM_TOT];
  const int tid = threadIdx.x;
  const int c   = blockIdx.x & 7;
  const int o   = (blockIdx.x >> 3) & 15;
  const int q   = blockIdx.x >> 7;
  const int tok0 = (q * 8 + c) * 256;

  const int lane = tid & 63;
  const int wave = tid >> 6;
  const int lo16 = lane & 15;
  const int quad = lane >> 4;
  const int row0 = wave * 16;
  unsigned short* sh = smem + SH_OFF;

  {  // stage W1' image (34.8 KB contiguous copy)
    const bf16x8* src = (const bf16x8*)(w1i + (size_t)o * SW1_SHORTS);
    for (int i = tid; i < SW1_SHORTS / 8; i += 256)
      *(bf16x8*)&smem[i * 8] = src[i];
  }

  // W0 A-frags (64 VGPR) + W2 A-frags (16 VGPR) -> registers, once per block
  const unsigned short* w0o = w0g + (size_t)o * HDIM * CIN;
  bf16x8 w0f[2][8];
#pragma unroll
  for (int ks = 0; ks < 2; ++ks)
#pragma unroll
    for (int nt = 0; nt < 8; ++nt)
      w0f[ks][nt] = *(const bf16x8*)
          &w0o[(size_t)(nt * 16 + lo16) * CIN + ks * 32 + quad * 8];
  const unsigned short* w2o = w2g + (size_t)o * F2 * HDIM;
  bf16x8 w2f[4];
#pragma unroll
  for (int ks = 0; ks < 4; ++ks)
    w2f[ks] = *(const bf16x8*)&w2o[lo16 * HDIM + ks * 32 + quad * 8];

  // bias base pointers (loads stay in-loop: L1-hot, frees 64 VGPRs)
  const float* pb0 = b0f + o * HDIM + quad * 4;
  const float* pb1 = b1f + o * HDIM + quad * 4;
  const f32x4 bias2 = *(const f32x4*)&b2f[o * F2 + quad * 4];
  __syncthreads();

  for (int mt = 0; mt < 4; ++mt) {
    const int trow = tok0 + wave * 64 + mt * 16;

    // ---- Layer 0: A=W0 (regs), B=x (bf16 image)
    f32x4 acc[8];
#pragma unroll
    for (int nt = 0; nt < 8; ++nt) acc[nt] = *(const f32x4*)&pb0[nt * 16];
#pragma unroll
    for (int ks = 0; ks < 2; ++ks) {
      bf16x8 bx = *(const bf16x8*)
          &xbf[(size_t)(trow + lo16) * CIN + ks * 32 + quad * 8];
#pragma unroll
      for (int nt = 0; nt < 8; ++nt)
        acc[nt] = __builtin_amdgcn_mfma_f32_16x16x32_bf16(w0f[ks][nt], bx, acc[nt], 0, 0, 0);
    }
    leaky_ln_store(acc, sh, row0 + lo16, quad);

    // ---- Layer 1: A=W1' (LDS), B=h
#pragma unroll
    for (int nt = 0; nt < 8; ++nt) acc[nt] = *(const f32x4*)&pb1[nt * 16];
#pragma unroll
    for (int ks = 0; ks < 4; ++ks) {
      bf16x8 bh = *(const bf16x8*)
          &sh[(row0 + lo16) * SH_STRIDE + ks * 32 + quad * 8];
#pragma unroll
      for (int nt = 0; nt < 8; ++nt) {
        bf16x8 a = *(const bf16x8*)
            &smem[(nt * 16 + lo16) * SW1_STRIDE + ks * 32 + quad * 8];
        acc[nt] = __builtin_amdgcn_mfma_f32_16x16x32_bf16(a, bh, acc[nt], 0, 0, 0);
      }
    }
    leaky_ln_store(acc, sh, row0 + lo16, quad);

    // ---- Layer 2: A=W2' (regs), B=h -> C[col=token][row=f]
    f32x4 acc2 = bias2;
#pragma unroll
    for (int ks = 0; ks < 4; ++ks) {
      bf16x8 bh = *(const bf16x8*)
          &sh[(row0 + lo16) * SH_STRIDE + ks * 32 + quad * 8];
      acc2 = __builtin_amdgcn_mfma_f32_16x16x32_bf16(w2f[ks], bh, acc2, 0, 0, 0);
    }
    // direct fp32 out[tok][f][o] (mapping validated R6)
    {
      const size_t ta = (size_t)(trow + lo16) * (F2 * O_CH);
#pragma unroll
      for (int r = 0; r < 4; ++r)
        out[ta + (quad * 4 + r) * O_CH + o] = leaky(acc2[r]);
    }
  }
}

extern "C" void kernel_launch(void* const* d_in, const int* in_sizes, int n_in,
                              void* d_out, int out_size, void* d_ws, size_t ws_size,
                              hipStream_t stream) {
  (void)in_sizes; (void)n_in; (void)out_size; (void)ws_size;
  const float* x   = (const float*)d_in[0];
  const float* W0  = (const float*)d_in[1];
  const float* b0  = (const float*)d_in[2];
  const float* g0  = (const float*)d_in[3];
  const float* be0 = (const float*)d_in[4];
  const float* W1  = (const float*)d_in[5];
  const float* b1  = (const float*)d_in[6];
  const float* g1  = (const float*)d_in[7];
  const float* be1 = (const float*)d_in[8];
  const float* W2  = (const float*)d_in[9];
  const float* b2  = (const float*)d_in[10];

  unsigned short* w0g = (unsigned short*)((char*)d_ws + W0G_OFF);
  unsigned short* w2g = (unsigned short*)((char*)d_ws + W2G_OFF);
  unsigned short* w1i = (unsigned short*)((char*)d_ws + W1I_OFF);
  unsigned short* xbf = (unsigned short*)((char*)d_ws + XBF_OFF);
  float* b0f = (float*)((char*)d_ws + B0F_OFF);
  float* b1f = (float*)((char*)d_ws + B1F_OFF);
  float* b2f = (float*)((char*)d_ws + B2F_OFF);

  prep<<<dim3(16 + (NTOK * CIN / 8) / 256), dim3(256), 0, stream>>>(
      x, W0, b0, g0, be0, W1, b1, g1, be1, W2, b2,
      w0g, w2g, w1i, xbf, b0f, b1f, b2f);
  film_main<<<dim3(O_CH * (NTOK / 256)), dim3(256), 0, stream>>>(
      xbf, w0g, w2g, w1i, b0f, b1f, b2f, (float*)d_out);
}

// Round 10
// 245.433 us; speedup vs baseline: 1.0228x; 1.0228x over previous
//
#include <hip/hip_runtime.h>
#include <hip/hip_bf16.h>

// FiLM block, MI355X. I/O fp32; compute bf16 MFMA (A=weights, B=tokens,
// C col=token), fp32 accum. R10: 3 blk/CU WITHOUT spill.
//  - R6's 16-token m-tile loop (R7/R8 showed 32-token super-tiles regress)
//  - LDS = W1' + 64-row h = 52.2 KB -> 3 blocks/CU (R9: occupancy 28% real)
//  - W0 A-frags streamed per-ks from bf16 global image (16 KB/block, L1-hot;
//    8 frags live at a time = 32 VGPR transient -> no spill, unlike R9)
//  - W2' frags in regs (16 VGPR); biases loaded in-loop (R9-validated)
//  - packed __float22bfloat162_rn h-stores + fma normalize (VALU cut)
#define NTOK  32768
#define CIN   64
#define HDIM  128
#define O_CH  16
#define F2    16
#define SLOPE 0.01f
#define EPS   1e-5f

// LDS (shorts): W1' padded image + 64-row h-buffer. stride 136: 16B-aligned
// rows, max 2-way bank conflict (free per m136).
#define SW1_STRIDE 136
#define SH_STRIDE  136
#define SW1_SHORTS (128 * SW1_STRIDE)    // 17408
#define SH_OFF     SW1_SHORTS
#define SMEM_TOT   (SW1_SHORTS + 64 * SH_STRIDE)  // 26112 sh = 52224 B -> 3 blk/CU

// d_ws layout (bytes); ~5.1 MB total. (R9-validated prep images.)
#define W0G_OFF    0
#define W0G_BYTES  ((size_t)O_CH * HDIM * CIN * 2)           // 262144
#define W2G_OFF    (W0G_OFF + W0G_BYTES)
#define W2G_BYTES  ((size_t)O_CH * F2 * HDIM * 2)            // 65536
#define W1I_OFF    (W2G_OFF + W2G_BYTES)
#define W1I_BYTES  ((size_t)O_CH * SW1_SHORTS * 2)           // 557056
#define XBF_OFF    (W1I_OFF + W1I_BYTES)
#define XBF_BYTES  ((size_t)NTOK * CIN * 2)                  // 4194304
#define B0F_OFF    (XBF_OFF + XBF_BYTES)
#define B0F_BYTES  ((size_t)O_CH * HDIM * 4)
#define B1F_OFF    (B0F_OFF + B0F_BYTES)
#define B1F_BYTES  ((size_t)O_CH * HDIM * 4)
#define B2F_OFF    (B1F_OFF + B1F_BYTES)
#define B2F_BYTES  ((size_t)O_CH * F2 * 4)

typedef __attribute__((ext_vector_type(8))) short bf16x8;
typedef __attribute__((ext_vector_type(4))) short bf16x4;
typedef __attribute__((ext_vector_type(4))) float f32x4;

__device__ __forceinline__ unsigned short f2b(float f) {
  union { float f; unsigned int i; } v;
  v.f = f;
  unsigned int i = v.i;
  unsigned int r = (i + 0x7fffu + ((i >> 16) & 1u)) >> 16;  // RNE
  return (unsigned short)r;
}
__device__ __forceinline__ float leaky(float t) {
  return fmaxf(t, SLOPE * t);   // == t>=0 ? t : 0.01t
}
__device__ __forceinline__ bf16x8 cvt8(const float* p) {
  float4 a = *(const float4*)p;
  float4 b = *(const float4*)(p + 4);
  bf16x8 r;
  r[0] = (short)f2b(a.x); r[1] = (short)f2b(a.y);
  r[2] = (short)f2b(a.z); r[3] = (short)f2b(a.w);
  r[4] = (short)f2b(b.x); r[5] = (short)f2b(b.y);
  r[6] = (short)f2b(b.z); r[7] = (short)f2b(b.w);
  return r;
}
__device__ __forceinline__ bf16x8 cvt8s(const float* p, const float* s) {
  bf16x8 r;
#pragma unroll
  for (int i = 0; i < 8; ++i) r[i] = (short)f2b(p[i] * s[i]);
  return r;
}

// leaky + LayerNorm on C-layout (col=token=lane&15, row=h). Lane holds 32 h
// of one token; butterfly xor 16,32 finishes the 128-sum. Packed bf16 cvt +
// uint2 (b64) store. sh NOT restrict (R5 post-mortem).
__device__ __forceinline__ void leaky_ln_store(
    const f32x4* acc, unsigned short* sh, int shrow, int quad) {
  float v[8][4];
  float s1 = 0.f, s2 = 0.f;
#pragma unroll
  for (int nt = 0; nt < 8; ++nt) {
#pragma unroll
    for (int r = 0; r < 4; ++r) {
      float t = leaky(acc[nt][r]);        // bias folded into C-init
      v[nt][r] = t;
      s1 += t;
      s2 += t * t;
    }
  }
  s1 += __shfl_xor(s1, 16); s2 += __shfl_xor(s2, 16);
  s1 += __shfl_xor(s1, 32); s2 += __shfl_xor(s2, 32);
  float mu = s1 * (1.0f / 128.0f);
  float var = s2 * (1.0f / 128.0f) - mu * mu;
  float rs = rsqrtf(var + EPS);
  float nm = -mu * rs;                    // y = v*rs + nm (one fma/elem)
#pragma unroll
  for (int nt = 0; nt < 8; ++nt) {
    __hip_bfloat162 p0 = __float22bfloat162_rn(
        make_float2(fmaf(v[nt][0], rs, nm), fmaf(v[nt][1], rs, nm)));
    __hip_bfloat162 p1 = __float22bfloat162_rn(
        make_float2(fmaf(v[nt][2], rs, nm), fmaf(v[nt][3], rs, nm)));
    uint2 pk;
    pk.x = *(unsigned int*)&p0;
    pk.y = *(unsigned int*)&p1;
    *(uint2*)&sh[shrow * SH_STRIDE + nt * 16 + quad * 4] = pk;
  }
}

// prep [R9-validated]: blocks 0..15 -> per-o images (W0 bf16 flat; W2'
// gamma-folded flat; W1' gamma-folded padded; folded biases). 16+ -> x bf16.
__global__ __launch_bounds__(256) void prep(
    const float* __restrict__ x,
    const float* __restrict__ W0, const float* __restrict__ b0,
    const float* __restrict__ g0, const float* __restrict__ be0,
    const float* __restrict__ W1, const float* __restrict__ b1,
    const float* __restrict__ g1, const float* __restrict__ be1,
    const float* __restrict__ W2, const float* __restrict__ b2,
    unsigned short* __restrict__ w0g, unsigned short* __restrict__ w2g,
    unsigned short* __restrict__ w1i, unsigned short* __restrict__ xbf,
    float* __restrict__ b0f, float* __restrict__ b1f,
    float* __restrict__ b2f) {
  const int bid = blockIdx.x, tid = threadIdx.x;
  if (bid < 16) {
    const int o = bid;
    __shared__ float sg0[HDIM], sbe0[HDIM], sg1[HDIM], sbe1[HDIM];
    if (tid < 128) {
      sg0[tid]  = g0 [o * HDIM + tid];
      sbe0[tid] = be0[o * HDIM + tid];
      sg1[tid]  = g1 [o * HDIM + tid];
      sbe1[tid] = be1[o * HDIM + tid];
    }
    __syncthreads();
    const float* w0 = W0 + (size_t)o * HDIM * CIN;
    for (int c = tid; c < (HDIM * CIN) / 8; c += 256)
      *(bf16x8*)&w0g[(size_t)o * HDIM * CIN + c * 8] = cvt8(w0 + c * 8);
    const float* w1 = W1 + (size_t)o * HDIM * HDIM;
    unsigned short* img = w1i + (size_t)o * SW1_SHORTS;
    for (int c = tid; c < (HDIM * HDIM) / 8; c += 256) {
      int n = c >> 4, k8 = c & 15;
      *(bf16x8*)&img[n * SW1_STRIDE + k8 * 8] =
          cvt8s(w1 + c * 8, sg0 + k8 * 8);           // W1' = W1 * g0[k]
    }
    const float* w2 = W2 + (size_t)o * F2 * HDIM;
    for (int c = tid; c < (F2 * HDIM) / 8; c += 256)
      *(bf16x8*)&w2g[(size_t)o * F2 * HDIM + c * 8] =
          cvt8s(w2 + c * 8, sg1 + (c & 15) * 8);     // W2' = W2 * g1[k]
    if (tid < 128) {
      b0f[o * HDIM + tid] = b0[o * HDIM + tid];
      float d = 0.f;
      const float* w1r = w1 + (size_t)tid * HDIM;
      for (int k = 0; k < HDIM; ++k) d += w1r[k] * sbe0[k];
      b1f[o * HDIM + tid] = b1[o * HDIM + tid] + d;  // b1' = b1 + W1*be0
    } else if (tid < 144) {
      int f = tid - 128;
      float d = 0.f;
      const float* w2r = w2 + (size_t)f * HDIM;
      for (int k = 0; k < HDIM; ++k) d += w2r[k] * sbe1[k];
      b2f[o * F2 + f] = b2[o * F2 + f] + d;          // b2' = b2 + W2*be1
    }
  } else {
    int idx = (bid - 16) * 256 + tid;
    *(bf16x8*)&xbf[(size_t)idx * 8] = cvt8(x + (size_t)idx * 8);
  }
}

// film_main: block = one o x 256 tokens (4 waves x 4 m-tiles of 16).
// W1' in LDS; W0 streamed per-ks from global bf16 image (L1-hot, 8 frags
// live -> no spill); W2' in regs. 52.2 KB LDS -> 3 blk/CU, 3 waves/SIMD.
// bid = q*128 + o*8 + c (XCD output write-combine, R6-validated).
__global__ __launch_bounds__(256, 3) void film_main(
    const unsigned short* __restrict__ xbf,
    const unsigned short* __restrict__ w0g,
    const unsigned short* __restrict__ w2g,
    const unsigned short* __restrict__ w1i,
    const float* __restrict__ b0f, const float* __restrict__ b1f,
    const float* __restrict__ b2f,
    float* __restrict__ out) {
  __shared__ unsigned short smem[SMEM_TOT];
  const int tid = threadIdx.x;
  const int c   = blockIdx.x & 7;
  const int o   = (blockIdx.x >> 3) & 15;
  const int q   = blockIdx.x >> 7;
  const int tok0 = (q * 8 + c) * 256;

  const int lane = tid & 63;
  const int wave = tid >> 6;
  const int lo16 = lane & 15;
  const int quad = lane >> 4;
  const int row0 = wave * 16;
  unsigned short* sh = smem + SH_OFF;

  {  // stage W1' image (34.8 KB contiguous copy)
    const bf16x8* src = (const bf16x8*)(w1i + (size_t)o * SW1_SHORTS);
    for (int i = tid; i < SW1_SHORTS / 8; i += 256)
      *(bf16x8*)&smem[i * 8] = src[i];
  }

  // W2' A-frags in regs (16 VGPR only)
  const unsigned short* w2o = w2g + (size_t)o * F2 * HDIM;
  bf16x8 w2f[4];
#pragma unroll
  for (int ks = 0; ks < 4; ++ks)
    w2f[ks] = *(const bf16x8*)&w2o[lo16 * HDIM + ks * 32 + quad * 8];

  const unsigned short* w0o = w0g + (size_t)o * HDIM * CIN;
  const float* pb0 = b0f + o * HDIM + quad * 4;   // bias loads in-loop (L1)
  const float* pb1 = b1f + o * HDIM + quad * 4;
  const f32x4 bias2 = *(const f32x4*)&b2f[o * F2 + quad * 4];
  __syncthreads();

  for (int mt = 0; mt < 4; ++mt) {
    const int trow = tok0 + wave * 64 + mt * 16;

    // ---- Layer 0: A=W0 (global bf16, L1-hot after mt=0; 8 frags/ks live)
    f32x4 acc[8];
#pragma unroll
    for (int nt = 0; nt < 8; ++nt) acc[nt] = *(const f32x4*)&pb0[nt * 16];
#pragma unroll
    for (int ks = 0; ks < 2; ++ks) {
      bf16x8 bx = *(const bf16x8*)
          &xbf[(size_t)(trow + lo16) * CIN + ks * 32 + quad * 8];
      bf16x8 a[8];
#pragma unroll
      for (int nt = 0; nt < 8; ++nt)
        a[nt] = *(const bf16x8*)
            &w0o[(size_t)(nt * 16 + lo16) * CIN + ks * 32 + quad * 8];
#pragma unroll
      for (int nt = 0; nt < 8; ++nt)
        acc[nt] = __builtin_amdgcn_mfma_f32_16x16x32_bf16(a[nt], bx, acc[nt], 0, 0, 0);
    }
    leaky_ln_store(acc, sh, row0 + lo16, quad);

    // ---- Layer 1: A=W1' (LDS), B=h
#pragma unroll
    for (int nt = 0; nt < 8; ++nt) acc[nt] = *(const f32x4*)&pb1[nt * 16];
#pragma unroll
    for (int ks = 0; ks < 4; ++ks) {
      bf16x8 bh = *(const bf16x8*)
          &sh[(row0 + lo16) * SH_STRIDE + ks * 32 + quad * 8];
#pragma unroll
      for (int nt = 0; nt < 8; ++nt) {
        bf16x8 a = *(const bf16x8*)
            &smem[(nt * 16 + lo16) * SW1_STRIDE + ks * 32 + quad * 8];
        acc[nt] = __builtin_amdgcn_mfma_f32_16x16x32_bf16(a, bh, acc[nt], 0, 0, 0);
      }
    }
    leaky_ln_store(acc, sh, row0 + lo16, quad);

    // ---- Layer 2: A=W2' (regs), B=h -> C[col=token][row=f]
    f32x4 acc2 = bias2;
#pragma unroll
    for (int ks = 0; ks < 4; ++ks) {
      bf16x8 bh = *(const bf16x8*)
          &sh[(row0 + lo16) * SH_STRIDE + ks * 32 + quad * 8];
      acc2 = __builtin_amdgcn_mfma_f32_16x16x32_bf16(w2f[ks], bh, acc2, 0, 0, 0);
    }
    // direct fp32 out[tok][f][o] (mapping validated R6)
    {
      const size_t ta = (size_t)(trow + lo16) * (F2 * O_CH);
#pragma unroll
      for (int r = 0; r < 4; ++r)
        out[ta + (quad * 4 + r) * O_CH + o] = leaky(acc2[r]);
    }
  }
}

extern "C" void kernel_launch(void* const* d_in, const int* in_sizes, int n_in,
                              void* d_out, int out_size, void* d_ws, size_t ws_size,
                              hipStream_t stream) {
  (void)in_sizes; (void)n_in; (void)out_size; (void)ws_size;
  const float* x   = (const float*)d_in[0];
  const float* W0  = (const float*)d_in[1];
  const float* b0  = (const float*)d_in[2];
  const float* g0  = (const float*)d_in[3];
  const float* be0 = (const float*)d_in[4];
  const float* W1  = (const float*)d_in[5];
  const float* b1  = (const float*)d_in[6];
  const float* g1  = (const float*)d_in[7];
  const float* be1 = (const float*)d_in[8];
  const float* W2  = (const float*)d_in[9];
  const float* b2  = (const float*)d_in[10];

  unsigned short* w0g = (unsigned short*)((char*)d_ws + W0G_OFF);
  unsigned short* w2g = (unsigned short*)((char*)d_ws + W2G_OFF);
  unsigned short* w1i = (unsigned short*)((char*)d_ws + W1I_OFF);
  unsigned short* xbf = (unsigned short*)((char*)d_ws + XBF_OFF);
  float* b0f = (float*)((char*)d_ws + B0F_OFF);
  float* b1f = (float*)((char*)d_ws + B1F_OFF);
  float* b2f = (float*)((char*)d_ws + B2F_OFF);

  prep<<<dim3(16 + (NTOK * CIN / 8) / 256), dim3(256), 0, stream>>>(
      x, W0, b0, g0, be0, W1, b1, g1, be1, W2, b2,
      w0g, w2g, w1i, xbf, b0f, b1f, b2f);
  film_main<<<dim3(O_CH * (NTOK / 256)), dim3(256), 0, stream>>>(
      xbf, w0g, w2g, w1i, b0f, b1f, b2f, (float*)d_out);
}

// Round 11
// 228.385 us; speedup vs baseline: 1.0992x; 1.0746x over previous
//
#include <hip/hip_runtime.h>
#include <hip/hip_bf16.h>

// FiLM block, MI355X. I/O fp32; compute bf16 MFMA (A=weights, B=tokens,
// C col=token), fp32 accum. R11 = R10 with the over-constrained
// __launch_bounds__(256,3) DROPPED (plain 256).
// R9/R10 post-mortem: the ",3" made the allocator budget 84 VGPRs (~512/6,
// over-constrained) -> all transients spilled -> 251 MB FETCH / 172 MB WRITE
// of scratch traffic, film 165 us. LDS=52.2 KB alone caps us at 3 blk/CU;
// natural VGPR (~110-140) keeps >=3 waves/SIMD without any forced bound.
#define NTOK  32768
#define CIN   64
#define HDIM  128
#define O_CH  16
#define F2    16
#define SLOPE 0.01f
#define EPS   1e-5f

// LDS (shorts): W1' padded image + 64-row h-buffer. stride 136: 16B-aligned
// rows, max 2-way bank conflict (free per m136).
#define SW1_STRIDE 136
#define SH_STRIDE  136
#define SW1_SHORTS (128 * SW1_STRIDE)    // 17408
#define SH_OFF     SW1_SHORTS
#define SMEM_TOT   (SW1_SHORTS + 64 * SH_STRIDE)  // 26112 sh = 52224 B -> 3 blk/CU

// d_ws layout (bytes); ~5.1 MB total. (R9-validated prep images.)
#define W0G_OFF    0
#define W0G_BYTES  ((size_t)O_CH * HDIM * CIN * 2)           // 262144
#define W2G_OFF    (W0G_OFF + W0G_BYTES)
#define W2G_BYTES  ((size_t)O_CH * F2 * HDIM * 2)            // 65536
#define W1I_OFF    (W2G_OFF + W2G_BYTES)
#define W1I_BYTES  ((size_t)O_CH * SW1_SHORTS * 2)           // 557056
#define XBF_OFF    (W1I_OFF + W1I_BYTES)
#define XBF_BYTES  ((size_t)NTOK * CIN * 2)                  // 4194304
#define B0F_OFF    (XBF_OFF + XBF_BYTES)
#define B0F_BYTES  ((size_t)O_CH * HDIM * 4)
#define B1F_OFF    (B0F_OFF + B0F_BYTES)
#define B1F_BYTES  ((size_t)O_CH * HDIM * 4)
#define B2F_OFF    (B1F_OFF + B1F_BYTES)
#define B2F_BYTES  ((size_t)O_CH * F2 * 4)

typedef __attribute__((ext_vector_type(8))) short bf16x8;
typedef __attribute__((ext_vector_type(4))) short bf16x4;
typedef __attribute__((ext_vector_type(4))) float f32x4;

__device__ __forceinline__ unsigned short f2b(float f) {
  union { float f; unsigned int i; } v;
  v.f = f;
  unsigned int i = v.i;
  unsigned int r = (i + 0x7fffu + ((i >> 16) & 1u)) >> 16;  // RNE
  return (unsigned short)r;
}
__device__ __forceinline__ float leaky(float t) {
  return fmaxf(t, SLOPE * t);   // == t>=0 ? t : 0.01t
}
__device__ __forceinline__ bf16x8 cvt8(const float* p) {
  float4 a = *(const float4*)p;
  float4 b = *(const float4*)(p + 4);
  bf16x8 r;
  r[0] = (short)f2b(a.x); r[1] = (short)f2b(a.y);
  r[2] = (short)f2b(a.z); r[3] = (short)f2b(a.w);
  r[4] = (short)f2b(b.x); r[5] = (short)f2b(b.y);
  r[6] = (short)f2b(b.z); r[7] = (short)f2b(b.w);
  return r;
}
__device__ __forceinline__ bf16x8 cvt8s(const float* p, const float* s) {
  bf16x8 r;
#pragma unroll
  for (int i = 0; i < 8; ++i) r[i] = (short)f2b(p[i] * s[i]);
  return r;
}

// leaky + LayerNorm on C-layout (col=token=lane&15, row=h). Lane holds 32 h
// of one token; butterfly xor 16,32 finishes the 128-sum. Packed bf16 cvt +
// uint2 (b64) store. sh NOT restrict (R5 post-mortem).
__device__ __forceinline__ void leaky_ln_store(
    const f32x4* acc, unsigned short* sh, int shrow, int quad) {
  float v[8][4];
  float s1 = 0.f, s2 = 0.f;
#pragma unroll
  for (int nt = 0; nt < 8; ++nt) {
#pragma unroll
    for (int r = 0; r < 4; ++r) {
      float t = leaky(acc[nt][r]);        // bias folded into C-init
      v[nt][r] = t;
      s1 += t;
      s2 += t * t;
    }
  }
  s1 += __shfl_xor(s1, 16); s2 += __shfl_xor(s2, 16);
  s1 += __shfl_xor(s1, 32); s2 += __shfl_xor(s2, 32);
  float mu = s1 * (1.0f / 128.0f);
  float var = s2 * (1.0f / 128.0f) - mu * mu;
  float rs = rsqrtf(var + EPS);
  float nm = -mu * rs;                    // y = v*rs + nm (one fma/elem)
#pragma unroll
  for (int nt = 0; nt < 8; ++nt) {
    __hip_bfloat162 p0 = __float22bfloat162_rn(
        make_float2(fmaf(v[nt][0], rs, nm), fmaf(v[nt][1], rs, nm)));
    __hip_bfloat162 p1 = __float22bfloat162_rn(
        make_float2(fmaf(v[nt][2], rs, nm), fmaf(v[nt][3], rs, nm)));
    uint2 pk;
    pk.x = *(unsigned int*)&p0;
    pk.y = *(unsigned int*)&p1;
    *(uint2*)&sh[shrow * SH_STRIDE + nt * 16 + quad * 4] = pk;
  }
}

// prep [R9-validated]: blocks 0..15 -> per-o images (W0 bf16 flat; W2'
// gamma-folded flat; W1' gamma-folded padded; folded biases). 16+ -> x bf16.
__global__ __launch_bounds__(256) void prep(
    const float* __restrict__ x,
    const float* __restrict__ W0, const float* __restrict__ b0,
    const float* __restrict__ g0, const float* __restrict__ be0,
    const float* __restrict__ W1, const float* __restrict__ b1,
    const float* __restrict__ g1, const float* __restrict__ be1,
    const float* __restrict__ W2, const float* __restrict__ b2,
    unsigned short* __restrict__ w0g, unsigned short* __restrict__ w2g,
    unsigned short* __restrict__ w1i, unsigned short* __restrict__ xbf,
    float* __restrict__ b0f, float* __restrict__ b1f,
    float* __restrict__ b2f) {
  const int bid = blockIdx.x, tid = threadIdx.x;
  if (bid < 16) {
    const int o = bid;
    __shared__ float sg0[HDIM], sbe0[HDIM], sg1[HDIM], sbe1[HDIM];
    if (tid < 128) {
      sg0[tid]  = g0 [o * HDIM + tid];
      sbe0[tid] = be0[o * HDIM + tid];
      sg1[tid]  = g1 [o * HDIM + tid];
      sbe1[tid] = be1[o * HDIM + tid];
    }
    __syncthreads();
    const float* w0 = W0 + (size_t)o * HDIM * CIN;
    for (int c = tid; c < (HDIM * CIN) / 8; c += 256)
      *(bf16x8*)&w0g[(size_t)o * HDIM * CIN + c * 8] = cvt8(w0 + c * 8);
    const float* w1 = W1 + (size_t)o * HDIM * HDIM;
    unsigned short* img = w1i + (size_t)o * SW1_SHORTS;
    for (int c = tid; c < (HDIM * HDIM) / 8; c += 256) {
      int n = c >> 4, k8 = c & 15;
      *(bf16x8*)&img[n * SW1_STRIDE + k8 * 8] =
          cvt8s(w1 + c * 8, sg0 + k8 * 8);           // W1' = W1 * g0[k]
    }
    const float* w2 = W2 + (size_t)o * F2 * HDIM;
    for (int c = tid; c < (F2 * HDIM) / 8; c += 256)
      *(bf16x8*)&w2g[(size_t)o * F2 * HDIM + c * 8] =
          cvt8s(w2 + c * 8, sg1 + (c & 15) * 8);     // W2' = W2 * g1[k]
    if (tid < 128) {
      b0f[o * HDIM + tid] = b0[o * HDIM + tid];
      float d = 0.f;
      const float* w1r = w1 + (size_t)tid * HDIM;
      for (int k = 0; k < HDIM; ++k) d += w1r[k] * sbe0[k];
      b1f[o * HDIM + tid] = b1[o * HDIM + tid] + d;  // b1' = b1 + W1*be0
    } else if (tid < 144) {
      int f = tid - 128;
      float d = 0.f;
      const float* w2r = w2 + (size_t)f * HDIM;
      for (int k = 0; k < HDIM; ++k) d += w2r[k] * sbe1[k];
      b2f[o * F2 + f] = b2[o * F2 + f] + d;          // b2' = b2 + W2*be1
    }
  } else {
    int idx = (bid - 16) * 256 + tid;
    *(bf16x8*)&xbf[(size_t)idx * 8] = cvt8(x + (size_t)idx * 8);
  }
}

// film_main: block = one o x 256 tokens (4 waves x 4 m-tiles of 16).
// W1' in LDS; W0 streamed per-ks from global bf16 image (L1/L2-hot); W2' in
// regs. 52.2 KB LDS -> 3 blk/CU (LDS-limited; VGPRs float free of bounds).
// bid = q*128 + o*8 + c (XCD output write-combine, R6-validated).
__global__ __launch_bounds__(256) void film_main(
    const unsigned short* __restrict__ xbf,
    const unsigned short* __restrict__ w0g,
    const unsigned short* __restrict__ w2g,
    const unsigned short* __restrict__ w1i,
    const float* __restrict__ b0f, const float* __restrict__ b1f,
    const float* __restrict__ b2f,
    float* __restrict__ out) {
  __shared__ unsigned short smem[SMEM_TOT];
  const int tid = threadIdx.x;
  const int c   = blockIdx.x & 7;
  const int o   = (blockIdx.x >> 3) & 15;
  const int q   = blockIdx.x >> 7;
  const int tok0 = (q * 8 + c) * 256;

  const int lane = tid & 63;
  const int wave = tid >> 6;
  const int lo16 = lane & 15;
  const int quad = lane >> 4;
  const int row0 = wave * 16;
  unsigned short* sh = smem + SH_OFF;

  {  // stage W1' image (34.8 KB contiguous copy)
    const bf16x8* src = (const bf16x8*)(w1i + (size_t)o * SW1_SHORTS);
    for (int i = tid; i < SW1_SHORTS / 8; i += 256)
      *(bf16x8*)&smem[i * 8] = src[i];
  }

  // W2' A-frags in regs (16 VGPR only)
  const unsigned short* w2o = w2g + (size_t)o * F2 * HDIM;
  bf16x8 w2f[4];
#pragma unroll
  for (int ks = 0; ks < 4; ++ks)
    w2f[ks] = *(const bf16x8*)&w2o[lo16 * HDIM + ks * 32 + quad * 8];

  const unsigned short* w0o = w0g + (size_t)o * HDIM * CIN;
  const float* pb0 = b0f + o * HDIM + quad * 4;   // bias loads in-loop (L1)
  const float* pb1 = b1f + o * HDIM + quad * 4;
  const f32x4 bias2 = *(const f32x4*)&b2f[o * F2 + quad * 4];
  __syncthreads();

  for (int mt = 0; mt < 4; ++mt) {
    const int trow = tok0 + wave * 64 + mt * 16;

    // ---- Layer 0: A=W0 (global bf16, L1-hot after mt=0; 8 frags/ks live)
    f32x4 acc[8];
#pragma unroll
    for (int nt = 0; nt < 8; ++nt) acc[nt] = *(const f32x4*)&pb0[nt * 16];
#pragma unroll
    for (int ks = 0; ks < 2; ++ks) {
      bf16x8 bx = *(const bf16x8*)
          &xbf[(size_t)(trow + lo16) * CIN + ks * 32 + quad * 8];
      bf16x8 a[8];
#pragma unroll
      for (int nt = 0; nt < 8; ++nt)
        a[nt] = *(const bf16x8*)
            &w0o[(size_t)(nt * 16 + lo16) * CIN + ks * 32 + quad * 8];
#pragma unroll
      for (int nt = 0; nt < 8; ++nt)
        acc[nt] = __builtin_amdgcn_mfma_f32_16x16x32_bf16(a[nt], bx, acc[nt], 0, 0, 0);
    }
    leaky_ln_store(acc, sh, row0 + lo16, quad);

    // ---- Layer 1: A=W1' (LDS), B=h
#pragma unroll
    for (int nt = 0; nt < 8; ++nt) acc[nt] = *(const f32x4*)&pb1[nt * 16];
#pragma unroll
    for (int ks = 0; ks < 4; ++ks) {
      bf16x8 bh = *(const bf16x8*)
          &sh[(row0 + lo16) * SH_STRIDE + ks * 32 + quad * 8];
#pragma unroll
      for (int nt = 0; nt < 8; ++nt) {
        bf16x8 a = *(const bf16x8*)
            &smem[(nt * 16 + lo16) * SW1_STRIDE + ks * 32 + quad * 8];
        acc[nt] = __builtin_amdgcn_mfma_f32_16x16x32_bf16(a, bh, acc[nt], 0, 0, 0);
      }
    }
    leaky_ln_store(acc, sh, row0 + lo16, quad);

    // ---- Layer 2: A=W2' (regs), B=h -> C[col=token][row=f]
    f32x4 acc2 = bias2;
#pragma unroll
    for (int ks = 0; ks < 4; ++ks) {
      bf16x8 bh = *(const bf16x8*)
          &sh[(row0 + lo16) * SH_STRIDE + ks * 32 + quad * 8];
      acc2 = __builtin_amdgcn_mfma_f32_16x16x32_bf16(w2f[ks], bh, acc2, 0, 0, 0);
    }
    // direct fp32 out[tok][f][o] (mapping validated R6)
    {
      const size_t ta = (size_t)(trow + lo16) * (F2 * O_CH);
#pragma unroll
      for (int r = 0; r < 4; ++r)
        out[ta + (quad * 4 + r) * O_CH + o] = leaky(acc2[r]);
    }
  }
}

extern "C" void kernel_launch(void* const* d_in, const int* in_sizes, int n_in,
                              void* d_out, int out_size, void* d_ws, size_t ws_size,
                              hipStream_t stream) {
  (void)in_sizes; (void)n_in; (void)out_size; (void)ws_size;
  const float* x   = (const float*)d_in[0];
  const float* W0  = (const float*)d_in[1];
  const float* b0  = (const float*)d_in[2];
  const float* g0  = (const float*)d_in[3];
  const float* be0 = (const float*)d_in[4];
  const float* W1  = (const float*)d_in[5];
  const float* b1  = (const float*)d_in[6];
  const float* g1  = (const float*)d_in[7];
  const float* be1 = (const float*)d_in[8];
  const float* W2  = (const float*)d_in[9];
  const float* b2  = (const float*)d_in[10];

  unsigned short* w0g = (unsigned short*)((char*)d_ws + W0G_OFF);
  unsigned short* w2g = (unsigned short*)((char*)d_ws + W2G_OFF);
  unsigned short* w1i = (unsigned short*)((char*)d_ws + W1I_OFF);
  unsigned short* xbf = (unsigned short*)((char*)d_ws + XBF_OFF);
  float* b0f = (float*)((char*)d_ws + B0F_OFF);
  float* b1f = (float*)((char*)d_ws + B1F_OFF);
  float* b2f = (float*)((char*)d_ws + B2F_OFF);

  prep<<<dim3(16 + (NTOK * CIN / 8) / 256), dim3(256), 0, stream>>>(
      x, W0, b0, g0, be0, W1, b1, g1, be1, W2, b2,
      w0g, w2g, w1i, xbf, b0f, b1f, b2f);
  film_main<<<dim3(O_CH * (NTOK / 256)), dim3(256), 0, stream>>>(
      xbf, w0g, w2g, w1i, b0f, b1f, b2f, (float*)d_out);
}